// Round 1
// baseline (3126.601 us; speedup 1.0000x reference)
//
#include <hip/hip_runtime.h>

// GCN 2-layer: out = A(relu(A x W1 + b1) W2) + b2, A = sym-normalized adj + self-loops.
// Strategy: aggregate BEFORE the linear where legal (linearity), keep the MLP fused.

__global__ void k_init_deg(float* __restrict__ deg, int n) {
    int i = blockIdx.x * blockDim.x + threadIdx.x;
    if (i < n) deg[i] = 1.0f;  // self-loop
}

__global__ void k_deg(const int* __restrict__ dst, float* __restrict__ deg, int E) {
    int e = blockIdx.x * blockDim.x + threadIdx.x;
    if (e < E) unsafeAtomicAdd(&deg[dst[e]], 1.0f);
}

// dinv = rsqrt(deg); aggx[i] = x[i] * dinv[i]^2  (self-loop message, doubles as init)
__global__ void k_dinv_selfloop(const float* __restrict__ x, float* __restrict__ deg_dinv,
                                float* __restrict__ aggx, int n) {
    int i = blockIdx.x * blockDim.x + threadIdx.x;
    if (i >= n) return;
    float dinv = rsqrtf(deg_dinv[i]);
    deg_dinv[i] = dinv;
    float w = dinv * dinv;
    const float4* xv = (const float4*)(x + (size_t)i * 16);
    float4* av = (float4*)(aggx + (size_t)i * 16);
#pragma unroll
    for (int q = 0; q < 4; ++q) {
        float4 v = xv[q];
        v.x *= w; v.y *= w; v.z *= w; v.w *= w;
        av[q] = v;
    }
}

// layer-1 scatter in input space (16 feats): aggx[dst] += x[src] * dinv[s]*dinv[d]
__global__ void k_scatter1(const int* __restrict__ src, const int* __restrict__ dst,
                           const float* __restrict__ x, const float* __restrict__ dinv,
                           float* __restrict__ aggx, int E) {
    int e = blockIdx.x * blockDim.x + threadIdx.x;
    if (e >= E) return;
    int s = src[e], d = dst[e];
    float nrm = dinv[s] * dinv[d];
    const float4* xv = (const float4*)(x + (size_t)s * 16);
    float* outp = aggx + (size_t)d * 16;
#pragma unroll
    for (int q = 0; q < 4; ++q) {
        float4 v = xv[q];
        unsafeAtomicAdd(outp + q * 4 + 0, v.x * nrm);
        unsafeAtomicAdd(outp + q * 4 + 1, v.y * nrm);
        unsafeAtomicAdd(outp + q * 4 + 2, v.z * nrm);
        unsafeAtomicAdd(outp + q * 4 + 3, v.w * nrm);
    }
}

// fused per-node MLP: h = relu(aggx @ W1 + b1); t = h @ W2; store t;
// out[i] = t * dinv^2 + b2  (self-loop term + bias = init for layer-2 scatter)
__global__ __launch_bounds__(256) void k_mlp(const float* __restrict__ aggx,
                                             const float* __restrict__ dinv,
                                             const float* __restrict__ W1,
                                             const float* __restrict__ b1,
                                             const float* __restrict__ W2,
                                             const float* __restrict__ b2,
                                             float* __restrict__ t,
                                             float* __restrict__ out, int n) {
    __shared__ float sW1[16 * 32];
    __shared__ float sW2[32 * 2];
    __shared__ float sb1[32];
    int tid = threadIdx.x;
    for (int k = tid; k < 16 * 32; k += 256) sW1[k] = W1[k];
    if (tid < 64) sW2[tid] = W2[tid];
    if (tid < 32) sb1[tid] = b1[tid];
    __syncthreads();
    int i = blockIdx.x * blockDim.x + tid;
    if (i >= n) return;
    float in[16];
    const float4* av = (const float4*)(aggx + (size_t)i * 16);
#pragma unroll
    for (int q = 0; q < 4; ++q) {
        float4 v = av[q];
        in[q * 4 + 0] = v.x; in[q * 4 + 1] = v.y;
        in[q * 4 + 2] = v.z; in[q * 4 + 3] = v.w;
    }
    float t0 = 0.f, t1 = 0.f;
#pragma unroll
    for (int j = 0; j < 32; ++j) {
        float acc = sb1[j];
#pragma unroll
        for (int k = 0; k < 16; ++k) acc = fmaf(in[k], sW1[k * 32 + j], acc);
        float h = fmaxf(acc, 0.f);
        t0 = fmaf(h, sW2[j * 2 + 0], t0);
        t1 = fmaf(h, sW2[j * 2 + 1], t1);
    }
    float di = dinv[i];
    float w = di * di;
    t[(size_t)i * 2 + 0] = t0;
    t[(size_t)i * 2 + 1] = t1;
    out[(size_t)i * 2 + 0] = fmaf(t0, w, b2[0]);
    out[(size_t)i * 2 + 1] = fmaf(t1, w, b2[1]);
}

// layer-2 scatter (2 feats): out[dst] += t[src] * dinv[s]*dinv[d]
__global__ void k_scatter2(const int* __restrict__ src, const int* __restrict__ dst,
                           const float* __restrict__ t, const float* __restrict__ dinv,
                           float* __restrict__ out, int E) {
    int e = blockIdx.x * blockDim.x + threadIdx.x;
    if (e >= E) return;
    int s = src[e], d = dst[e];
    float nrm = dinv[s] * dinv[d];
    float2 tv = *(const float2*)(t + (size_t)s * 2);
    unsafeAtomicAdd(out + (size_t)d * 2 + 0, tv.x * nrm);
    unsafeAtomicAdd(out + (size_t)d * 2 + 1, tv.y * nrm);
}

extern "C" void kernel_launch(void* const* d_in, const int* in_sizes, int n_in,
                              void* d_out, int out_size, void* d_ws, size_t ws_size,
                              hipStream_t stream) {
    const float* x  = (const float*)d_in[0];
    const int*   ei = (const int*)d_in[1];
    const float* W1 = (const float*)d_in[2];
    const float* b1 = (const float*)d_in[3];
    const float* W2 = (const float*)d_in[4];
    const float* b2 = (const float*)d_in[5];
    float* out = (float*)d_out;

    const int n = in_sizes[0] / 16;
    const int E = in_sizes[1] / 2;
    const int* src = ei;
    const int* dst = ei + E;

    // workspace layout (floats): deg/dinv [n] | aggx [n*16] | t [n*2]
    float* deg  = (float*)d_ws;
    float* aggx = deg + n;
    float* t    = aggx + (size_t)n * 16;

    const int B = 256;
    const int gn = (n + B - 1) / B;
    const int ge = (E + B - 1) / B;

    k_init_deg<<<gn, B, 0, stream>>>(deg, n);
    k_deg<<<ge, B, 0, stream>>>(dst, deg, E);
    k_dinv_selfloop<<<gn, B, 0, stream>>>(x, deg, aggx, n);
    k_scatter1<<<ge, B, 0, stream>>>(src, dst, x, deg, aggx, E);
    k_mlp<<<gn, B, 0, stream>>>(aggx, deg, W1, b1, W2, b2, t, out, n);
    k_scatter2<<<ge, B, 0, stream>>>(src, dst, t, deg, out, E);
}

// Round 2
// 690.492 us; speedup vs baseline: 4.5281x; 4.5281x over previous
//
#include <hip/hip_runtime.h>

// GCN 2-layer: out = A(relu(A x W1 + b1) W2) + b2, A = sym-normalized adj + self-loops.
// R2 strategy: build CSR (counting sort by dst) each call -> convert scatters to gathers.
// Atomics drop 57.6M f32 -> 6.4M int (memory-side RMW was the R1 bottleneck: 1.64GB WRITE_SIZE).

#define THREADS 256

// ---------------- CSR build ----------------

__global__ void k_zero(int* __restrict__ cnt, int n) {
    int i = blockIdx.x * blockDim.x + threadIdx.x;
    if (i < n) cnt[i] = 0;
}

__global__ void k_hist(const int* __restrict__ dst, int* __restrict__ cnt, int E) {
    int e = blockIdx.x * blockDim.x + threadIdx.x;
    if (e < E) atomicAdd(&cnt[dst[e]], 1);
}

// single-block exclusive scan over n counts -> rowptr[n+1]; also dinv = rsqrt(cnt+1)
__global__ __launch_bounds__(1024) void k_scan(const int* __restrict__ cnt,
                                               int* __restrict__ rowptr,
                                               float* __restrict__ dinv, int n) {
    __shared__ int s[1024];
    int tid = threadIdx.x;
    int chunk = (n + 1023) / 1024;
    int start = tid * chunk;
    int end = min(start + chunk, n);
    int sum = 0;
    for (int i = start; i < end; ++i) sum += cnt[i];
    s[tid] = sum;
    __syncthreads();
    for (int off = 1; off < 1024; off <<= 1) {
        int v = (tid >= off) ? s[tid - off] : 0;
        __syncthreads();
        s[tid] += v;
        __syncthreads();
    }
    int base = s[tid] - sum;  // exclusive prefix of this thread's chunk
    for (int i = start; i < end; ++i) {
        rowptr[i] = base;
        int c = cnt[i];
        base += c;
        dinv[i] = rsqrtf((float)(c + 1));  // +1 self-loop
    }
    if (start < n && end == n) rowptr[n] = base;
}

// place each edge's src into its dst's CSR slot (atomicSub leaves cnt at 0)
__global__ void k_fill(const int* __restrict__ src, const int* __restrict__ dst,
                       const int* __restrict__ rowptr, int* __restrict__ cnt,
                       int* __restrict__ col, int E) {
    int e = blockIdx.x * blockDim.x + threadIdx.x;
    if (e >= E) return;
    int d = dst[e];
    int pos = rowptr[d] + atomicSub(&cnt[d], 1) - 1;
    col[pos] = src[e];
}

// ---------------- layer 1 gather (input space, 16 feats) + fused MLP ----------------
// agg = dinv_i^2 * x_i + sum_j dinv_sj*dinv_i * x_sj ; t = relu(agg W1 + b1) W2
__global__ __launch_bounds__(256) void k_l1(const float* __restrict__ x,
                                            const int* __restrict__ rowptr,
                                            const int* __restrict__ col,
                                            const float* __restrict__ dinv,
                                            const float* __restrict__ W1,
                                            const float* __restrict__ b1,
                                            const float* __restrict__ W2,
                                            float* __restrict__ t, int n) {
    __shared__ float sW1[16 * 32];
    __shared__ float sW2[32 * 2];
    __shared__ float sb1[32];
    int tid = threadIdx.x;
    for (int k = tid; k < 512; k += 256) sW1[k] = W1[k];
    if (tid < 64) sW2[tid] = W2[tid];
    if (tid < 32) sb1[tid] = b1[tid];
    __syncthreads();
    int i = blockIdx.x * blockDim.x + tid;
    if (i >= n) return;
    float di = dinv[i];
    float w0 = di * di;
    float agg[16];
    const float4* xv = (const float4*)(x + (size_t)i * 16);
#pragma unroll
    for (int q = 0; q < 4; ++q) {
        float4 v = xv[q];
        agg[4 * q + 0] = v.x * w0; agg[4 * q + 1] = v.y * w0;
        agg[4 * q + 2] = v.z * w0; agg[4 * q + 3] = v.w * w0;
    }
    int beg = rowptr[i], fin = rowptr[i + 1];
    for (int j = beg; j < fin; ++j) {
        int s = col[j];
        float w = dinv[s] * di;
        const float4* sv = (const float4*)(x + (size_t)s * 16);
#pragma unroll
        for (int q = 0; q < 4; ++q) {
            float4 v = sv[q];
            agg[4 * q + 0] = fmaf(v.x, w, agg[4 * q + 0]);
            agg[4 * q + 1] = fmaf(v.y, w, agg[4 * q + 1]);
            agg[4 * q + 2] = fmaf(v.z, w, agg[4 * q + 2]);
            agg[4 * q + 3] = fmaf(v.w, w, agg[4 * q + 3]);
        }
    }
    float t0 = 0.f, t1 = 0.f;
#pragma unroll
    for (int j = 0; j < 32; ++j) {
        float acc = sb1[j];
#pragma unroll
        for (int k = 0; k < 16; ++k) acc = fmaf(agg[k], sW1[k * 32 + j], acc);
        float h = fmaxf(acc, 0.f);
        t0 = fmaf(h, sW2[j * 2 + 0], t0);
        t1 = fmaf(h, sW2[j * 2 + 1], t1);
    }
    t[(size_t)i * 2 + 0] = t0;
    t[(size_t)i * 2 + 1] = t1;
}

// ---------------- layer 2 gather (2 feats) ----------------
__global__ void k_l2(const int* __restrict__ rowptr, const int* __restrict__ col,
                     const float* __restrict__ dinv, const float* __restrict__ t,
                     const float* __restrict__ b2, float* __restrict__ out, int n) {
    int i = blockIdx.x * blockDim.x + threadIdx.x;
    if (i >= n) return;
    float di = dinv[i];
    float2 ts = *(const float2*)(t + (size_t)i * 2);
    float acc0 = ts.x * di * di, acc1 = ts.y * di * di;
    int beg = rowptr[i], fin = rowptr[i + 1];
    for (int j = beg; j < fin; ++j) {
        int s = col[j];
        float w = dinv[s] * di;
        float2 tv = *(const float2*)(t + (size_t)s * 2);
        acc0 = fmaf(tv.x, w, acc0);
        acc1 = fmaf(tv.y, w, acc1);
    }
    out[(size_t)i * 2 + 0] = acc0 + b2[0];
    out[(size_t)i * 2 + 1] = acc1 + b2[1];
}

// ---------------- R1 fallback (scatter w/ float atomics) if ws too small ----------------

__global__ void k_init_deg(float* __restrict__ deg, int n) {
    int i = blockIdx.x * blockDim.x + threadIdx.x;
    if (i < n) deg[i] = 1.0f;
}
__global__ void k_deg(const int* __restrict__ dst, float* __restrict__ deg, int E) {
    int e = blockIdx.x * blockDim.x + threadIdx.x;
    if (e < E) unsafeAtomicAdd(&deg[dst[e]], 1.0f);
}
__global__ void k_dinv_selfloop(const float* __restrict__ x, float* __restrict__ deg_dinv,
                                float* __restrict__ aggx, int n) {
    int i = blockIdx.x * blockDim.x + threadIdx.x;
    if (i >= n) return;
    float dinv = rsqrtf(deg_dinv[i]);
    deg_dinv[i] = dinv;
    float w = dinv * dinv;
    const float4* xv = (const float4*)(x + (size_t)i * 16);
    float4* av = (float4*)(aggx + (size_t)i * 16);
#pragma unroll
    for (int q = 0; q < 4; ++q) {
        float4 v = xv[q];
        v.x *= w; v.y *= w; v.z *= w; v.w *= w;
        av[q] = v;
    }
}
__global__ void k_scatter1(const int* __restrict__ src, const int* __restrict__ dst,
                           const float* __restrict__ x, const float* __restrict__ dinv,
                           float* __restrict__ aggx, int E) {
    int e = blockIdx.x * blockDim.x + threadIdx.x;
    if (e >= E) return;
    int s = src[e], d = dst[e];
    float nrm = dinv[s] * dinv[d];
    const float4* xv = (const float4*)(x + (size_t)s * 16);
    float* outp = aggx + (size_t)d * 16;
#pragma unroll
    for (int q = 0; q < 4; ++q) {
        float4 v = xv[q];
        unsafeAtomicAdd(outp + q * 4 + 0, v.x * nrm);
        unsafeAtomicAdd(outp + q * 4 + 1, v.y * nrm);
        unsafeAtomicAdd(outp + q * 4 + 2, v.z * nrm);
        unsafeAtomicAdd(outp + q * 4 + 3, v.w * nrm);
    }
}
__global__ __launch_bounds__(256) void k_mlp(const float* __restrict__ aggx,
                                             const float* __restrict__ dinv,
                                             const float* __restrict__ W1,
                                             const float* __restrict__ b1,
                                             const float* __restrict__ W2,
                                             const float* __restrict__ b2,
                                             float* __restrict__ t,
                                             float* __restrict__ out, int n) {
    __shared__ float sW1[16 * 32];
    __shared__ float sW2[32 * 2];
    __shared__ float sb1[32];
    int tid = threadIdx.x;
    for (int k = tid; k < 512; k += 256) sW1[k] = W1[k];
    if (tid < 64) sW2[tid] = W2[tid];
    if (tid < 32) sb1[tid] = b1[tid];
    __syncthreads();
    int i = blockIdx.x * blockDim.x + tid;
    if (i >= n) return;
    float in[16];
    const float4* av = (const float4*)(aggx + (size_t)i * 16);
#pragma unroll
    for (int q = 0; q < 4; ++q) {
        float4 v = av[q];
        in[4 * q + 0] = v.x; in[4 * q + 1] = v.y;
        in[4 * q + 2] = v.z; in[4 * q + 3] = v.w;
    }
    float t0 = 0.f, t1 = 0.f;
#pragma unroll
    for (int j = 0; j < 32; ++j) {
        float acc = sb1[j];
#pragma unroll
        for (int k = 0; k < 16; ++k) acc = fmaf(in[k], sW1[k * 32 + j], acc);
        float h = fmaxf(acc, 0.f);
        t0 = fmaf(h, sW2[j * 2 + 0], t0);
        t1 = fmaf(h, sW2[j * 2 + 1], t1);
    }
    float di = dinv[i];
    float w = di * di;
    t[(size_t)i * 2 + 0] = t0;
    t[(size_t)i * 2 + 1] = t1;
    out[(size_t)i * 2 + 0] = fmaf(t0, w, b2[0]);
    out[(size_t)i * 2 + 1] = fmaf(t1, w, b2[1]);
}
__global__ void k_scatter2(const int* __restrict__ src, const int* __restrict__ dst,
                           const float* __restrict__ t, const float* __restrict__ dinv,
                           float* __restrict__ out, int E) {
    int e = blockIdx.x * blockDim.x + threadIdx.x;
    if (e >= E) return;
    int s = src[e], d = dst[e];
    float nrm = dinv[s] * dinv[d];
    float2 tv = *(const float2*)(t + (size_t)s * 2);
    unsafeAtomicAdd(out + (size_t)d * 2 + 0, tv.x * nrm);
    unsafeAtomicAdd(out + (size_t)d * 2 + 1, tv.y * nrm);
}

extern "C" void kernel_launch(void* const* d_in, const int* in_sizes, int n_in,
                              void* d_out, int out_size, void* d_ws, size_t ws_size,
                              hipStream_t stream) {
    const float* x  = (const float*)d_in[0];
    const int*   ei = (const int*)d_in[1];
    const float* W1 = (const float*)d_in[2];
    const float* b1 = (const float*)d_in[3];
    const float* W2 = (const float*)d_in[4];
    const float* b2 = (const float*)d_in[5];
    float* out = (float*)d_out;

    const int n = in_sizes[0] / 16;
    const int E = in_sizes[1] / 2;
    const int* src = ei;
    const int* dst = ei + E;

    const int B = 256;
    const int gn = (n + B - 1) / B;
    const int ge = (E + B - 1) / B;

    // CSR-path workspace: cnt[n] | rowptr[n+1] | col[E] | dinv[n] | t[2n]  (ints/floats, 4B)
    size_t need = (size_t)(n + (n + 1) + E + n + 2 * n) * 4 + 64;
    if (ws_size >= need) {
        int*   cnt    = (int*)d_ws;
        int*   rowptr = cnt + n;
        int*   col    = rowptr + (n + 1);
        float* dinv   = (float*)(col + E);
        float* t      = dinv + n;

        k_zero<<<gn, B, 0, stream>>>(cnt, n);
        k_hist<<<ge, B, 0, stream>>>(dst, cnt, E);
        k_scan<<<1, 1024, 0, stream>>>(cnt, rowptr, dinv, n);
        k_fill<<<ge, B, 0, stream>>>(src, dst, rowptr, cnt, col, E);
        k_l1<<<gn, B, 0, stream>>>(x, rowptr, col, dinv, W1, b1, W2, t, n);
        k_l2<<<gn, B, 0, stream>>>(rowptr, col, dinv, t, b2, out, n);
    } else {
        // R1 fallback: deg/dinv [n] | aggx [n*16] | t [2n]
        float* deg  = (float*)d_ws;
        float* aggx = deg + n;
        float* t    = aggx + (size_t)n * 16;
        k_init_deg<<<gn, B, 0, stream>>>(deg, n);
        k_deg<<<ge, B, 0, stream>>>(dst, deg, E);
        k_dinv_selfloop<<<gn, B, 0, stream>>>(x, deg, aggx, n);
        k_scatter1<<<ge, B, 0, stream>>>(src, dst, x, deg, aggx, E);
        k_mlp<<<gn, B, 0, stream>>>(aggx, deg, W1, b1, W2, b2, t, out, n);
        k_scatter2<<<ge, B, 0, stream>>>(src, dst, t, deg, out, E);
    }
}

// Round 3
// 332.902 us; speedup vs baseline: 9.3920x; 2.0742x over previous
//
#include <hip/hip_runtime.h>

// GCN 2-layer: out = A(relu(A x W1 + b1) W2) + b2, A = sym-normalized adj + self-loops.
// R3: multi-block scan (R2's single-block scan was 226us = 33% of total) and
// atomic-free k_fill (rank captured from k_hist's atomicAdd return).

#define B 256

// ---------------- CSR build ----------------

__global__ void k_zero(int* __restrict__ cnt, int n) {
    int i = blockIdx.x * blockDim.x + threadIdx.x;
    if (i < n) cnt[i] = 0;
}

// rank path: remember each edge's arrival order within its dst row
__global__ void k_hist_rank(const int* __restrict__ dst, int* __restrict__ cnt,
                            int* __restrict__ rank, int E) {
    int e = blockIdx.x * blockDim.x + threadIdx.x;
    if (e < E) rank[e] = atomicAdd(&cnt[dst[e]], 1);
}

__global__ void k_hist(const int* __restrict__ dst, int* __restrict__ cnt, int E) {
    int e = blockIdx.x * blockDim.x + threadIdx.x;
    if (e < E) atomicAdd(&cnt[dst[e]], 1);
}

// --- hierarchical exclusive scan over cnt[n] -> rowptr, plus dinv = rsqrt(cnt+1) ---
// chunk = 1024 nodes/block (256 threads x 4 items)

__global__ __launch_bounds__(256) void k_blocksum(const int* __restrict__ cnt,
                                                  int* __restrict__ bsum, int n) {
    __shared__ int s[256];
    int tid = threadIdx.x;
    int base = blockIdx.x * 1024 + tid * 4;
    int sum = 0;
#pragma unroll
    for (int q = 0; q < 4; ++q) {
        int i = base + q;
        if (i < n) sum += cnt[i];
    }
    s[tid] = sum;
    __syncthreads();
    for (int off = 128; off > 0; off >>= 1) {
        if (tid < off) s[tid] += s[tid + off];
        __syncthreads();
    }
    if (tid == 0) bsum[blockIdx.x] = s[0];
}

// single small block: exclusive scan of per-block sums (nb <= 1024); also rowptr[n]=E
__global__ __launch_bounds__(1024) void k_scan_bsums(const int* __restrict__ bsum,
                                                     int* __restrict__ boff, int nb,
                                                     int* __restrict__ rowptr, int n, int E) {
    __shared__ int s[1024];
    int tid = threadIdx.x;
    int v = (tid < nb) ? bsum[tid] : 0;
    s[tid] = v;
    __syncthreads();
    for (int off = 1; off < 1024; off <<= 1) {
        int u = (tid >= off) ? s[tid - off] : 0;
        __syncthreads();
        s[tid] += u;
        __syncthreads();
    }
    if (tid < nb) boff[tid] = s[tid] - v;  // exclusive
    if (tid == 0) rowptr[n] = E;
}

__global__ __launch_bounds__(256) void k_scan_apply(const int* __restrict__ cnt,
                                                    const int* __restrict__ boff,
                                                    int* __restrict__ rowptr,
                                                    float* __restrict__ dinv, int n) {
    __shared__ int s[256];
    int tid = threadIdx.x;
    int base = blockIdx.x * 1024 + tid * 4;
    int c[4];
    int sum = 0;
#pragma unroll
    for (int q = 0; q < 4; ++q) {
        int i = base + q;
        c[q] = (i < n) ? cnt[i] : 0;
        sum += c[q];
    }
    s[tid] = sum;
    __syncthreads();
    for (int off = 1; off < 256; off <<= 1) {
        int u = (tid >= off) ? s[tid - off] : 0;
        __syncthreads();
        s[tid] += u;
        __syncthreads();
    }
    int run = boff[blockIdx.x] + s[tid] - sum;
#pragma unroll
    for (int q = 0; q < 4; ++q) {
        int i = base + q;
        if (i < n) {
            rowptr[i] = run;
            run += c[q];
            dinv[i] = rsqrtf((float)(c[q] + 1));
        }
    }
}

// atomic-free fill using precomputed rank
__global__ void k_fill_rank(const int* __restrict__ src, const int* __restrict__ dst,
                            const int* __restrict__ rowptr, const int* __restrict__ rank,
                            int* __restrict__ col, int E) {
    int e = blockIdx.x * blockDim.x + threadIdx.x;
    if (e >= E) return;
    int d = dst[e];
    col[rowptr[d] + rank[e]] = src[e];
}

// fallback fill (atomicSub leaves cnt at 0)
__global__ void k_fill(const int* __restrict__ src, const int* __restrict__ dst,
                       const int* __restrict__ rowptr, int* __restrict__ cnt,
                       int* __restrict__ col, int E) {
    int e = blockIdx.x * blockDim.x + threadIdx.x;
    if (e >= E) return;
    int d = dst[e];
    int pos = rowptr[d] + atomicSub(&cnt[d], 1) - 1;
    col[pos] = src[e];
}

// ---------------- layer 1 gather (input space, 16 feats) + fused MLP ----------------
__global__ __launch_bounds__(256) void k_l1(const float* __restrict__ x,
                                            const int* __restrict__ rowptr,
                                            const int* __restrict__ col,
                                            const float* __restrict__ dinv,
                                            const float* __restrict__ W1,
                                            const float* __restrict__ b1,
                                            const float* __restrict__ W2,
                                            float* __restrict__ t, int n) {
    __shared__ float sW1[16 * 32];
    __shared__ float sW2[32 * 2];
    __shared__ float sb1[32];
    int tid = threadIdx.x;
    for (int k = tid; k < 512; k += 256) sW1[k] = W1[k];
    if (tid < 64) sW2[tid] = W2[tid];
    if (tid < 32) sb1[tid] = b1[tid];
    __syncthreads();
    int i = blockIdx.x * blockDim.x + tid;
    if (i >= n) return;
    float di = dinv[i];
    float w0 = di * di;
    float agg[16];
    const float4* xv = (const float4*)(x + (size_t)i * 16);
#pragma unroll
    for (int q = 0; q < 4; ++q) {
        float4 v = xv[q];
        agg[4 * q + 0] = v.x * w0; agg[4 * q + 1] = v.y * w0;
        agg[4 * q + 2] = v.z * w0; agg[4 * q + 3] = v.w * w0;
    }
    int beg = rowptr[i], fin = rowptr[i + 1];
    for (int j = beg; j < fin; ++j) {
        int s = col[j];
        float w = dinv[s] * di;
        const float4* sv = (const float4*)(x + (size_t)s * 16);
#pragma unroll
        for (int q = 0; q < 4; ++q) {
            float4 v = sv[q];
            agg[4 * q + 0] = fmaf(v.x, w, agg[4 * q + 0]);
            agg[4 * q + 1] = fmaf(v.y, w, agg[4 * q + 1]);
            agg[4 * q + 2] = fmaf(v.z, w, agg[4 * q + 2]);
            agg[4 * q + 3] = fmaf(v.w, w, agg[4 * q + 3]);
        }
    }
    float t0 = 0.f, t1 = 0.f;
#pragma unroll
    for (int j = 0; j < 32; ++j) {
        float acc = sb1[j];
#pragma unroll
        for (int k = 0; k < 16; ++k) acc = fmaf(agg[k], sW1[k * 32 + j], acc);
        float h = fmaxf(acc, 0.f);
        t0 = fmaf(h, sW2[j * 2 + 0], t0);
        t1 = fmaf(h, sW2[j * 2 + 1], t1);
    }
    t[(size_t)i * 2 + 0] = t0;
    t[(size_t)i * 2 + 1] = t1;
}

// ---------------- layer 2 gather (2 feats) ----------------
__global__ void k_l2(const int* __restrict__ rowptr, const int* __restrict__ col,
                     const float* __restrict__ dinv, const float* __restrict__ t,
                     const float* __restrict__ b2, float* __restrict__ out, int n) {
    int i = blockIdx.x * blockDim.x + threadIdx.x;
    if (i >= n) return;
    float di = dinv[i];
    float2 ts = *(const float2*)(t + (size_t)i * 2);
    float acc0 = ts.x * di * di, acc1 = ts.y * di * di;
    int beg = rowptr[i], fin = rowptr[i + 1];
    for (int j = beg; j < fin; ++j) {
        int s = col[j];
        float w = dinv[s] * di;
        float2 tv = *(const float2*)(t + (size_t)s * 2);
        acc0 = fmaf(tv.x, w, acc0);
        acc1 = fmaf(tv.y, w, acc1);
    }
    out[(size_t)i * 2 + 0] = acc0 + b2[0];
    out[(size_t)i * 2 + 1] = acc1 + b2[1];
}

// ---------------- R1 fallback (scatter w/ float atomics) ----------------

__global__ void k_init_deg(float* __restrict__ deg, int n) {
    int i = blockIdx.x * blockDim.x + threadIdx.x;
    if (i < n) deg[i] = 1.0f;
}
__global__ void k_deg(const int* __restrict__ dst, float* __restrict__ deg, int E) {
    int e = blockIdx.x * blockDim.x + threadIdx.x;
    if (e < E) unsafeAtomicAdd(&deg[dst[e]], 1.0f);
}
__global__ void k_dinv_selfloop(const float* __restrict__ x, float* __restrict__ deg_dinv,
                                float* __restrict__ aggx, int n) {
    int i = blockIdx.x * blockDim.x + threadIdx.x;
    if (i >= n) return;
    float dinv = rsqrtf(deg_dinv[i]);
    deg_dinv[i] = dinv;
    float w = dinv * dinv;
    const float4* xv = (const float4*)(x + (size_t)i * 16);
    float4* av = (float4*)(aggx + (size_t)i * 16);
#pragma unroll
    for (int q = 0; q < 4; ++q) {
        float4 v = xv[q];
        v.x *= w; v.y *= w; v.z *= w; v.w *= w;
        av[q] = v;
    }
}
__global__ void k_scatter1(const int* __restrict__ src, const int* __restrict__ dst,
                           const float* __restrict__ x, const float* __restrict__ dinv,
                           float* __restrict__ aggx, int E) {
    int e = blockIdx.x * blockDim.x + threadIdx.x;
    if (e >= E) return;
    int s = src[e], d = dst[e];
    float nrm = dinv[s] * dinv[d];
    const float4* xv = (const float4*)(x + (size_t)s * 16);
    float* outp = aggx + (size_t)d * 16;
#pragma unroll
    for (int q = 0; q < 4; ++q) {
        float4 v = xv[q];
        unsafeAtomicAdd(outp + q * 4 + 0, v.x * nrm);
        unsafeAtomicAdd(outp + q * 4 + 1, v.y * nrm);
        unsafeAtomicAdd(outp + q * 4 + 2, v.z * nrm);
        unsafeAtomicAdd(outp + q * 4 + 3, v.w * nrm);
    }
}
__global__ __launch_bounds__(256) void k_mlp(const float* __restrict__ aggx,
                                             const float* __restrict__ dinv,
                                             const float* __restrict__ W1,
                                             const float* __restrict__ b1,
                                             const float* __restrict__ W2,
                                             const float* __restrict__ b2,
                                             float* __restrict__ t,
                                             float* __restrict__ out, int n) {
    __shared__ float sW1[16 * 32];
    __shared__ float sW2[32 * 2];
    __shared__ float sb1[32];
    int tid = threadIdx.x;
    for (int k = tid; k < 512; k += 256) sW1[k] = W1[k];
    if (tid < 64) sW2[tid] = W2[tid];
    if (tid < 32) sb1[tid] = b1[tid];
    __syncthreads();
    int i = blockIdx.x * blockDim.x + tid;
    if (i >= n) return;
    float in[16];
    const float4* av = (const float4*)(aggx + (size_t)i * 16);
#pragma unroll
    for (int q = 0; q < 4; ++q) {
        float4 v = av[q];
        in[4 * q + 0] = v.x; in[4 * q + 1] = v.y;
        in[4 * q + 2] = v.z; in[4 * q + 3] = v.w;
    }
    float t0 = 0.f, t1 = 0.f;
#pragma unroll
    for (int j = 0; j < 32; ++j) {
        float acc = sb1[j];
#pragma unroll
        for (int k = 0; k < 16; ++k) acc = fmaf(in[k], sW1[k * 32 + j], acc);
        float h = fmaxf(acc, 0.f);
        t0 = fmaf(h, sW2[j * 2 + 0], t0);
        t1 = fmaf(h, sW2[j * 2 + 1], t1);
    }
    float di = dinv[i];
    float w = di * di;
    t[(size_t)i * 2 + 0] = t0;
    t[(size_t)i * 2 + 1] = t1;
    out[(size_t)i * 2 + 0] = fmaf(t0, w, b2[0]);
    out[(size_t)i * 2 + 1] = fmaf(t1, w, b2[1]);
}
__global__ void k_scatter2(const int* __restrict__ src, const int* __restrict__ dst,
                           const float* __restrict__ t, const float* __restrict__ dinv,
                           float* __restrict__ out, int E) {
    int e = blockIdx.x * blockDim.x + threadIdx.x;
    if (e >= E) return;
    int s = src[e], d = dst[e];
    float nrm = dinv[s] * dinv[d];
    float2 tv = *(const float2*)(t + (size_t)s * 2);
    unsafeAtomicAdd(out + (size_t)d * 2 + 0, tv.x * nrm);
    unsafeAtomicAdd(out + (size_t)d * 2 + 1, tv.y * nrm);
}

extern "C" void kernel_launch(void* const* d_in, const int* in_sizes, int n_in,
                              void* d_out, int out_size, void* d_ws, size_t ws_size,
                              hipStream_t stream) {
    const float* x  = (const float*)d_in[0];
    const int*   ei = (const int*)d_in[1];
    const float* W1 = (const float*)d_in[2];
    const float* b1 = (const float*)d_in[3];
    const float* W2 = (const float*)d_in[4];
    const float* b2 = (const float*)d_in[5];
    float* out = (float*)d_out;

    const int n = in_sizes[0] / 16;
    const int E = in_sizes[1] / 2;
    const int* src = ei;
    const int* dst = ei + E;

    const int gn = (n + B - 1) / B;
    const int ge = (E + B - 1) / B;
    const int nb = (n + 1023) / 1024;  // scan blocks (<=1024 assumed; n<=1M)

    size_t tmax = (size_t)(E > 2 * n ? E : 2 * n);
    // rank path: cnt[n] | rowptr[n+1] | col[E] | dinv[n] | bsum[nb] | boff[nb] | rank/t[tmax]
    size_t need_rank   = ((size_t)(3 * n + 1 + 2 * nb) + E + tmax) * 4 + 64;
    // norank path: cnt[n] | rowptr[n+1] | col[E] | dinv[n] | bsum[nb] | boff[nb] | t[2n]
    size_t need_norank = ((size_t)(5 * n + 1 + 2 * nb) + E) * 4 + 64;

    if (ws_size >= need_norank && nb <= 1024) {
        int*   cnt    = (int*)d_ws;
        int*   rowptr = cnt + n;
        int*   col    = rowptr + (n + 1);
        float* dinv   = (float*)(col + E);
        int*   bsum   = (int*)(dinv + n);
        int*   boff   = bsum + nb;
        int*   rank   = boff + nb;          // rank path only; dead after k_fill_rank
        float* t      = (float*)rank;       // aliases rank (live from k_l1 on)

        bool use_rank = (ws_size >= need_rank);

        k_zero<<<gn, B, 0, stream>>>(cnt, n);
        if (use_rank)
            k_hist_rank<<<ge, B, 0, stream>>>(dst, cnt, rank, E);
        else
            k_hist<<<ge, B, 0, stream>>>(dst, cnt, E);
        k_blocksum<<<nb, 256, 0, stream>>>(cnt, bsum, n);
        k_scan_bsums<<<1, 1024, 0, stream>>>(bsum, boff, nb, rowptr, n, E);
        k_scan_apply<<<nb, 256, 0, stream>>>(cnt, boff, rowptr, dinv, n);
        if (use_rank)
            k_fill_rank<<<ge, B, 0, stream>>>(src, dst, rowptr, rank, col, E);
        else
            k_fill<<<ge, B, 0, stream>>>(src, dst, rowptr, cnt, col, E);
        k_l1<<<gn, B, 0, stream>>>(x, rowptr, col, dinv, W1, b1, W2, t, n);
        k_l2<<<gn, B, 0, stream>>>(rowptr, col, dinv, t, b2, out, n);
    } else {
        // R1 fallback: deg/dinv [n] | aggx [n*16] | t [2n]
        float* deg  = (float*)d_ws;
        float* aggx = deg + n;
        float* t    = aggx + (size_t)n * 16;
        k_init_deg<<<gn, B, 0, stream>>>(deg, n);
        k_deg<<<ge, B, 0, stream>>>(dst, deg, E);
        k_dinv_selfloop<<<gn, B, 0, stream>>>(x, deg, aggx, n);
        k_scatter1<<<ge, B, 0, stream>>>(src, dst, x, deg, aggx, E);
        k_mlp<<<gn, B, 0, stream>>>(aggx, deg, W1, b1, W2, b2, t, out, n);
        k_scatter2<<<ge, B, 0, stream>>>(src, dst, t, deg, out, E);
    }
}